// Round 1
// baseline (54.199 us; speedup 1.0000x reference)
//
#include <hip/hip_runtime.h>
#include <math.h>

#define EPS_COS 1e-8f
#define EPS_ADD 1e-12f

// B=256 batches, one block per batch. N=4096 rows, M=64 cols, S=3 shift taps.
// Block = 1024 threads = 16 waves. Each 16-lane subgroup handles one row's
// dot product + norm via float4 loads (fully coalesced: 64 lanes x 16B = 1KiB
// per wave load instruction).

constexpr int NTHREADS = 1024;
constexpr int NWAVES   = NTHREADS / 64;   // 16
constexpr int MAX_N    = 4096;            // LDS buffers sized for this

__global__ __launch_bounds__(NTHREADS, 1) void ntm_attention_kernel(
    const float* __restrict__ beta,    // [B,1]
    const float* __restrict__ kappa,   // [B,64]
    const float* __restrict__ gamma,   // [B,1]
    const float* __restrict__ g,       // [B,1]
    const float* __restrict__ s,       // [B,S]
    const float* __restrict__ w_prev,  // [B,N]
    const float* __restrict__ mem,     // [B,N,64]
    float* __restrict__ out,           // [B,N]
    int N, int S)
{
    const int b    = blockIdx.x;
    const int tid  = threadIdx.x;
    const int lane = tid & 63;
    const int wave = tid >> 6;
    const int l16  = lane & 15;   // position within the 16-lane row group
    const int rgrp = lane >> 4;   // which of the 4 rows this wave handles

    __shared__ float t_sh[MAX_N];   // scores -> exp values -> sharpened values
    __shared__ float w_sh[MAX_N];   // interpolated weights (for the shift)
    __shared__ float red[NWAVES];

    // ---- kappa fragment: lane l16 holds kappa[4*l16 .. 4*l16+3] (+eps) ----
    float4 kv = *reinterpret_cast<const float4*>(kappa + (size_t)b * 64 + l16 * 4);
    kv.x += EPS_ADD; kv.y += EPS_ADD; kv.z += EPS_ADD; kv.w += EPS_ADD;

    float nb2 = kv.x * kv.x + kv.y * kv.y + kv.z * kv.z + kv.w * kv.w;
#pragma unroll
    for (int m = 1; m < 16; m <<= 1) nb2 += __shfl_xor(nb2, m);
    const float nb = fmaxf(sqrtf(nb2), EPS_COS);
    const float bv = beta[b];

    // ---- main pass over memory: scores t[n] = beta * cos_sim(mem[n], kappa) ----
    const size_t base = (size_t)b * N * 64;
    float tmax = -INFINITY;

    const int nIter = N / 64;        // 64 rows per block-iteration (16 waves x 4 rows)
    // assumes N % 256 == 0 (N = 4096 here)
    for (int it = 0; it < nIter; it += 4) {
        const int row0 = it * 64 + wave * 4 + rgrp;
        const float4* p = reinterpret_cast<const float4*>(mem + base + (size_t)row0 * 64) + l16;
        // rows spaced 64 apart -> 64*64 floats = 1024 float4s apart
        float4 a0 = p[0];
        float4 a1 = p[1024];
        float4 a2 = p[2048];
        float4 a3 = p[3072];

#pragma unroll
        for (int k = 0; k < 4; ++k) {
            float4 a = (k == 0) ? a0 : (k == 1) ? a1 : (k == 2) ? a2 : a3;
            a.x += EPS_ADD; a.y += EPS_ADD; a.z += EPS_ADD; a.w += EPS_ADD;
            float d  = a.x * kv.x + a.y * kv.y + a.z * kv.z + a.w * kv.w;
            float n2 = a.x * a.x + a.y * a.y + a.z * a.z + a.w * a.w;
#pragma unroll
            for (int m = 1; m < 16; m <<= 1) {
                d  += __shfl_xor(d, m);
                n2 += __shfl_xor(n2, m);
            }
            const float na = fmaxf(sqrtf(n2), EPS_COS);
            const float t  = bv * (d / (na * nb));
            const int row  = row0 + k * 64;
            if (l16 == 0) t_sh[row] = t;
            tmax = fmaxf(tmax, t);
        }
    }

    // ---- block-wide max ----
#pragma unroll
    for (int m = 1; m < 64; m <<= 1) tmax = fmaxf(tmax, __shfl_xor(tmax, m));
    if (lane == 0) red[wave] = tmax;
    __syncthreads();
    float gmax = red[0];
#pragma unroll
    for (int i = 1; i < NWAVES; ++i) gmax = fmaxf(gmax, red[i]);
    __syncthreads();

    // ---- exp + sum ----
    float lsum = 0.0f;
    for (int i = tid; i < N; i += NTHREADS) {
        const float e = expf(t_sh[i] - gmax);
        t_sh[i] = e;
        lsum += e;
    }
#pragma unroll
    for (int m = 1; m < 64; m <<= 1) lsum += __shfl_xor(lsum, m);
    if (lane == 0) red[wave] = lsum;
    __syncthreads();
    float tot = 0.0f;
#pragma unroll
    for (int i = 0; i < NWAVES; ++i) tot += red[i];
    __syncthreads();

    // ---- w_c = softmax, interpolate with w_prev ----
    const float gv = g[b];
    for (int i = tid; i < N; i += NTHREADS) {
        const float wc = t_sh[i] / tot;
        const float wp = w_prev[(size_t)b * N + i];
        w_sh[i] = gv * wc + (1.0f - gv) * wp;
    }
    __syncthreads();

    // ---- circular shift + sharpen ----
    const float gam = gamma[b];
    float sv[8];
    const int Sc = (S < 8) ? S : 8;
    for (int j = 0; j < Sc; ++j) sv[j] = s[(size_t)b * S + j];

    float ssum = 0.0f;
    for (int i = tid; i < N; i += NTHREADS) {
        float wh = 0.0f;
        for (int j = 0; j < Sc; ++j) {
            int idx = i + j - 1;
            idx += N;            // i+j-1 in [-1, N+1]
            if (idx >= N) idx -= N;
            if (idx >= N) idx -= N;
            wh += sv[j] * w_sh[idx];
        }
        const float sh = powf(wh, gam);
        t_sh[i] = sh;
        ssum += sh;
    }
#pragma unroll
    for (int m = 1; m < 64; m <<= 1) ssum += __shfl_xor(ssum, m);
    if (lane == 0) red[wave] = ssum;
    __syncthreads();
    float stot = 0.0f;
#pragma unroll
    for (int i = 0; i < NWAVES; ++i) stot += red[i];

    // ---- normalize + write out ----
    const float denom = stot + EPS_ADD;
    for (int i = tid; i < N; i += NTHREADS) {
        out[(size_t)b * N + i] = t_sh[i] / denom;
    }
}

extern "C" void kernel_launch(void* const* d_in, const int* in_sizes, int n_in,
                              void* d_out, int out_size, void* d_ws, size_t ws_size,
                              hipStream_t stream) {
    const float* beta   = (const float*)d_in[0];
    const float* kappa  = (const float*)d_in[1];
    const float* gamma  = (const float*)d_in[2];
    const float* g      = (const float*)d_in[3];
    const float* s      = (const float*)d_in[4];
    const float* w_prev = (const float*)d_in[5];
    const float* mem    = (const float*)d_in[6];
    float* out          = (float*)d_out;

    const int B = in_sizes[0];            // beta is (B,1)
    const int N = in_sizes[5] / B;        // w_prev is (B,N)
    const int S = in_sizes[4] / B;        // s is (B,S)
    // M assumed == 64 (in_sizes[1]/B); kernel layout depends on it.

    ntm_attention_kernel<<<B, NTHREADS, 0, stream>>>(
        beta, kappa, gamma, g, s, w_prev, mem, out, N, S);
}